// Round 13
// baseline (958.412 us; speedup 1.0000x reference)
//
#include <hip/hip_runtime.h>

static constexpr int T_S   = 512;
static constexpr int H_DIM = 2816;
static constexpr int HD_   = 256;
static constexpr int N_E   = 32;
static constexpr int TOPK_ = 4;
static constexpr int I_DIM = 704;
static constexpr int Q_N   = 4096;
static constexpr int KV_N  = 2048;
static constexpr int QKV_N = 8192;
static constexpr int NSLOT = 2048;               // T_S * TOPK_
static constexpr float EPS_ = 1e-6f;

typedef __attribute__((ext_vector_type(4))) float f32x4;
typedef __attribute__((ext_vector_type(8))) short bf16x8;

static __device__ __forceinline__ ushort f2bf(float f) {
  uint u = __float_as_uint(f);
  u += 0x7fffu + ((u >> 16) & 1u);
  return (ushort)(u >> 16);
}
static __device__ __forceinline__ float bf2f(ushort u) {
  return __uint_as_float((uint)u << 16);
}
static __device__ __forceinline__ void split2(float x, ushort& h, ushort& l2) {
  h = f2bf(x);
  l2 = f2bf(x - bf2f(h));
}
static __device__ __forceinline__ void split8(const float4& a, const float4& b,
                                              uint4& H, uint4& L) {
  ushort h0,l0,h1,l1,h2,l2,h3,l3,h4,l4,h5,l5,h6,l6,h7,l7;
  split2(a.x,h0,l0); split2(a.y,h1,l1); split2(a.z,h2,l2); split2(a.w,h3,l3);
  split2(b.x,h4,l4); split2(b.y,h5,l5); split2(b.z,h6,l6); split2(b.w,h7,l7);
  H = (uint4){ (uint)h0|((uint)h1<<16), (uint)h2|((uint)h3<<16),
               (uint)h4|((uint)h5<<16), (uint)h6|((uint)h7<<16) };
  L = (uint4){ (uint)l0|((uint)l1<<16), (uint)l2|((uint)l3<<16),
               (uint)l4|((uint)l5<<16), (uint)l6|((uint)l7<<16) };
}
static __device__ __forceinline__ uint4 pack8(const float4& a, const float4& b) {
  return (uint4){ (uint)f2bf(a.x)|((uint)f2bf(a.y)<<16), (uint)f2bf(a.z)|((uint)f2bf(a.w)<<16),
                  (uint)f2bf(b.x)|((uint)f2bf(b.y)<<16), (uint)f2bf(b.z)|((uint)f2bf(b.w)<<16) };
}

static __device__ __forceinline__ float wave_sum(float v) {
  #pragma unroll
  for (int off = 1; off < 64; off <<= 1) v += __shfl_xor(v, off);
  return v;
}
static __device__ __forceinline__ float block_sum256(float v, float* sm) {
  v = wave_sum(v);
  int w = threadIdx.x >> 6, l = threadIdx.x & 63;
  if (l == 0) sm[w] = v;
  __syncthreads();
  float r = sm[0] + sm[1] + sm[2] + sm[3];
  __syncthreads();
  return r;
}

// ---------------- input RMSNorm -> bf16 hi/lo ----------------
__global__ __launch_bounds__(256) void k_ln_in(
    const float* __restrict__ hid, const float* __restrict__ w,
    ushort* __restrict__ hhi, ushort* __restrict__ hlo) {
  __shared__ float sm[4];
  int t = blockIdx.x, tid = threadIdx.x;
  const float* row = hid + (size_t)t * H_DIM;
  float x[11]; float s = 0.f;
  #pragma unroll
  for (int j = 0; j < 11; ++j) { x[j] = row[tid + j*256]; s += x[j]*x[j]; }
  s = block_sum256(s, sm);
  float r = rsqrtf(s / (float)H_DIM + EPS_);
  #pragma unroll
  for (int j = 0; j < 11; ++j) {
    int idx = tid + j*256;
    float val = x[j]*r*w[idx];
    ushort h, l2; split2(val, h, l2);
    hhi[(size_t)t*H_DIM + idx] = h;
    hlo[(size_t)t*H_DIM + idx] = l2;
  }
}

// ---------------- QKV GEMM, split-bf16, K-sliced ----------------
__global__ __launch_bounds__(256, 2) void k_gemm_qkv(
    const ushort* __restrict__ Ah, const ushort* __restrict__ Al,
    const float* __restrict__ qw, const float* __restrict__ kw,
    const float* __restrict__ vw, float* __restrict__ Cp) {
  const int K = H_DIM, KS = H_DIM/2, NSs = KS/32;
  __shared__ ushort Ash[4][129][8], Asl[4][129][8];
  __shared__ ushort Bsh[4][65][8],  Bsl[4][65][8];
  int tid = threadIdx.x, w = tid >> 6, l = tid & 63;
  int n0 = blockIdx.x * 64, m0 = blockIdx.y * 128, kz = blockIdx.z;
  int kbase = kz * KS;
  const float* Bp = (n0 < Q_N) ? qw + (size_t)n0*K
                  : (n0 < Q_N+KV_N) ? kw + (size_t)(n0-Q_N)*K
                  : vw + (size_t)(n0-Q_N-KV_N)*K;
  float* C = Cp + (size_t)kz * T_S * QKV_N;
  const int l15 = l & 15, lq = l >> 4;
  const int wm = w >> 1, wn = w & 1;
  const int sar = tid >> 2, sak = tid & 3;
  const ushort* aph = Ah + (size_t)(m0 + sar)*K + kbase + sak*8;
  const ushort* apl = Al + (size_t)(m0 + sar)*K + kbase + sak*8;
  const float*  bp  = Bp + (size_t)sar*K + kbase + sak*8;
  uint4 arh0 = *(const uint4*)(aph);
  uint4 arh1 = *(const uint4*)(aph + (size_t)64*K);
  uint4 arl0 = *(const uint4*)(apl);
  uint4 arl1 = *(const uint4*)(apl + (size_t)64*K);
  float4 brA = *(const float4*)(bp), brB = *(const float4*)(bp + 4);
  f32x4 acc[4][2];
  #pragma unroll
  for (int a = 0; a < 4; ++a)
    #pragma unroll
    for (int b = 0; b < 2; ++b) acc[a][b] = (f32x4){0.f,0.f,0.f,0.f};
  for (int t = 0; t < NSs; ++t) {
    *(uint4*)&Ash[sak][sar][0]    = arh0;
    *(uint4*)&Ash[sak][64+sar][0] = arh1;
    *(uint4*)&Asl[sak][sar][0]    = arl0;
    *(uint4*)&Asl[sak][64+sar][0] = arl1;
    { uint4 H, L; split8(brA, brB, H, L);
      *(uint4*)&Bsh[sak][sar][0] = H;
      *(uint4*)&Bsl[sak][sar][0] = L; }
    __syncthreads();
    if (t + 1 < NSs) {
      int k0 = (t+1)*32;
      arh0 = *(const uint4*)(aph + k0);
      arh1 = *(const uint4*)(aph + (size_t)64*K + k0);
      arl0 = *(const uint4*)(apl + k0);
      arl1 = *(const uint4*)(apl + (size_t)64*K + k0);
      brA = *(const float4*)(bp + k0); brB = *(const float4*)(bp + k0 + 4);
    }
    bf16x8 bh[2], bl[2];
    #pragma unroll
    for (int nf = 0; nf < 2; ++nf) {
      bh[nf] = *(bf16x8*)&Bsh[lq][wn*32 + nf*16 + l15][0];
      bl[nf] = *(bf16x8*)&Bsl[lq][wn*32 + nf*16 + l15][0];
    }
    #pragma unroll
    for (int mf = 0; mf < 4; ++mf) {
      bf16x8 ah = *(bf16x8*)&Ash[lq][wm*64 + mf*16 + l15][0];
      bf16x8 al = *(bf16x8*)&Asl[lq][wm*64 + mf*16 + l15][0];
      #pragma unroll
      for (int nf = 0; nf < 2; ++nf) {
        acc[mf][nf] = __builtin_amdgcn_mfma_f32_16x16x32_bf16(ah, bh[nf], acc[mf][nf], 0, 0, 0);
        acc[mf][nf] = __builtin_amdgcn_mfma_f32_16x16x32_bf16(ah, bl[nf], acc[mf][nf], 0, 0, 0);
        acc[mf][nf] = __builtin_amdgcn_mfma_f32_16x16x32_bf16(al, bh[nf], acc[mf][nf], 0, 0, 0);
      }
    }
    __syncthreads();
  }
  #pragma unroll
  for (int mf = 0; mf < 4; ++mf)
    #pragma unroll
    for (int nf = 0; nf < 2; ++nf)
      #pragma unroll
      for (int r = 0; r < 4; ++r)
        C[(size_t)(m0 + wm*64 + mf*16 + lq*4 + r)*QKV_N + n0 + wn*32 + nf*16 + l15] = acc[mf][nf][r];
}

// ---------------- per-(token,head) norm + RoPE (sums 2 K-slices) ----------------
__global__ __launch_bounds__(64) void k_norm_rope(
    const float* __restrict__ qkvf0, const float* __restrict__ qkvf1,
    const float* __restrict__ cosb, const float* __restrict__ sinb,
    const float* __restrict__ qnw, const float* __restrict__ knw,
    ushort* __restrict__ qh, ushort* __restrict__ ql,
    ushort* __restrict__ vth, ushort* __restrict__ vtl) {
  int bid = blockIdx.x;
  int token = bid >> 5, ch = bid & 31;
  int l = threadIdx.x;
  int col; const float* wp = nullptr; bool rope = true; int vch = -1;
  if (ch < 16)      { col = ch*HD_; wp = qnw; }
  else if (ch < 24) { col = Q_N + (ch-16)*HD_; wp = knw; }
  else              { col = Q_N + KV_N + (ch-24)*HD_; rope = false; vch = ch-24; }
  size_t base = (size_t)token*QKV_N + col;
  float4 va = *(const float4*)(qkvf0 + base + l*4);
  float4 vb = *(const float4*)(qkvf1 + base + l*4);
  float4 v = { va.x+vb.x, va.y+vb.y, va.z+vb.z, va.w+vb.w };
  float s = v.x*v.x + v.y*v.y + v.z*v.z + v.w*v.w;
  s = wave_sum(s);
  float r = rsqrtf(s / (float)HD_ + EPS_);
  float n0 = v.x*r, n1 = v.y*r, n2 = v.z*r, n3 = v.w*r;
  if (wp) { float4 w4 = *(const float4*)(wp + l*4); n0*=w4.x; n1*=w4.y; n2*=w4.z; n3*=w4.w; }
  float o0 = n0, o1 = n1, o2 = n2, o3 = n3;
  if (rope) {
    float p0 = __shfl_xor(n0, 32), p1 = __shfl_xor(n1, 32),
          p2 = __shfl_xor(n2, 32), p3 = __shfl_xor(n3, 32);
    float sg = (l < 32) ? -1.f : 1.f;
    float4 c4 = *(const float4*)(cosb + (size_t)token*HD_ + l*4);
    float4 s4 = *(const float4*)(sinb + (size_t)token*HD_ + l*4);
    o0 = n0*c4.x + sg*p0*s4.x;
    o1 = n1*c4.y + sg*p1*s4.y;
    o2 = n2*c4.z + sg*p2*s4.z;
    o3 = n3*c4.w + sg*p3*s4.w;
  }
  ushort h0,e0,h1,e1,h2,e2,h3,e3;
  split2(o0,h0,e0); split2(o1,h1,e1); split2(o2,h2,e2); split2(o3,h3,e3);
  ushort4 pkh = {h0,h1,h2,h3}, pkl = {e0,e1,e2,e3};
  *(ushort4*)(qh + base + l*4) = pkh;
  *(ushort4*)(ql + base + l*4) = pkl;
  if (vch >= 0) {
    size_t vb2 = ((size_t)vch*HD_)*T_S + token;
    vth[vb2 + (size_t)(l*4+0)*T_S] = pkh.x; vth[vb2 + (size_t)(l*4+1)*T_S] = pkh.y;
    vth[vb2 + (size_t)(l*4+2)*T_S] = pkh.z; vth[vb2 + (size_t)(l*4+3)*T_S] = pkh.w;
    vtl[vb2 + (size_t)(l*4+0)*T_S] = pkl.x; vtl[vb2 + (size_t)(l*4+1)*T_S] = pkl.y;
    vtl[vb2 + (size_t)(l*4+2)*T_S] = pkl.z; vtl[vb2 + (size_t)(l*4+3)*T_S] = pkl.w;
  }
}

// ---------------- flash attention (causal, no scale, GQA 2:1), split-bf16 ----------------
__global__ __launch_bounds__(256, 1) void k_attn(
    const ushort* __restrict__ qbh, const ushort* __restrict__ qbl,
    const ushort* __restrict__ vth, const ushort* __restrict__ vtl,
    ushort* __restrict__ ohi, ushort* __restrict__ olo) {
  __shared__ ushort kbh[32][64][8], kbl[32][64][8];
  __shared__ ushort vbh[8][256][8], vbl[8][256][8];
  __shared__ ushort pbh[4][8][16][8], pbl[4][8][16][8];
  int qt = blockIdx.x, h = blockIdx.y, kvh = h >> 1;
  int tid = threadIdx.x, w = tid >> 6, l = tid & 63;
  int l15 = l & 15, lq = l >> 4;
  int qb = qt * 64;
  bf16x8 qfh[8], qfl[8];
  {
    size_t qoff = (size_t)(qb + w*16 + l15)*QKV_N + h*HD_ + lq*8;
    #pragma unroll
    for (int kc = 0; kc < 8; ++kc) {
      qfh[kc] = *(const bf16x8*)(qbh + qoff + kc*32);
      qfl[kc] = *(const bf16x8*)(qbl + qoff + kc*32);
    }
  }
  f32x4 oacc[16];
  #pragma unroll
  for (int i = 0; i < 16; ++i) oacc[i] = (f32x4){0.f,0.f,0.f,0.f};
  float mrun[4] = {-1e30f,-1e30f,-1e30f,-1e30f};
  float lrun[4] = {0.f,0.f,0.f,0.f};
  for (int jt = 0; jt <= qt; ++jt) {
    int jb = jt * 64;
    #pragma unroll
    for (int i = 0; i < 8; ++i) {
      int c = i*256 + tid, kc8 = c & 31, kv = c >> 5;
      size_t goff = (size_t)(jb+kv)*QKV_N + Q_N + kvh*HD_ + kc8*8;
      *(uint4*)&kbh[kc8][kv ^ (kc8 & 7)][0] = *(const uint4*)(qbh + goff);
      *(uint4*)&kbl[kc8][kv ^ (kc8 & 7)][0] = *(const uint4*)(qbl + goff);
    }
    #pragma unroll
    for (int i = 0; i < 8; ++i) {
      int c = i*256 + tid, d = c >> 3, k8 = c & 7;
      size_t goff = ((size_t)kvh*HD_ + d)*T_S + jb + k8*8;
      *(uint4*)&vbh[k8][d ^ (k8 & 7)][0] = *(const uint4*)(vth + goff);
      *(uint4*)&vbl[k8][d ^ (k8 & 7)][0] = *(const uint4*)(vtl + goff);
    }
    __syncthreads();
    f32x4 sf[4];
    #pragma unroll
    for (int nf = 0; nf < 4; ++nf) sf[nf] = (f32x4){0.f,0.f,0.f,0.f};
    #pragma unroll
    for (int kc = 0; kc < 8; ++kc) {
      #pragma unroll
      for (int nf = 0; nf < 4; ++nf) {
        int kv = nf*16 + l15, kc8 = kc*4 + lq;
        bf16x8 kfh = *(bf16x8*)&kbh[kc8][kv ^ (kc8 & 7)][0];
        bf16x8 kfl = *(bf16x8*)&kbl[kc8][kv ^ (kc8 & 7)][0];
        sf[nf] = __builtin_amdgcn_mfma_f32_16x16x32_bf16(qfh[kc], kfh, sf[nf], 0, 0, 0);
        sf[nf] = __builtin_amdgcn_mfma_f32_16x16x32_bf16(qfh[kc], kfl, sf[nf], 0, 0, 0);
        sf[nf] = __builtin_amdgcn_mfma_f32_16x16x32_bf16(qfl[kc], kfh, sf[nf], 0, 0, 0);
      }
    }
    if (jt == qt) {
      #pragma unroll
      for (int nf = 0; nf < 4; ++nf) {
        int kvg = jb + nf*16 + l15;
        #pragma unroll
        for (int r = 0; r < 4; ++r) {
          int qg = qb + w*16 + lq*4 + r;
          if (kvg > qg) sf[nf][r] = -3.0e38f;
        }
      }
    }
    float mnew[4], scale[4], rs[4];
    #pragma unroll
    for (int r = 0; r < 4; ++r) {
      float m = fmaxf(fmaxf(sf[0][r], sf[1][r]), fmaxf(sf[2][r], sf[3][r]));
      #pragma unroll
      for (int off = 1; off < 16; off <<= 1) m = fmaxf(m, __shfl_xor(m, off));
      mnew[r] = fmaxf(mrun[r], m);
      scale[r] = __expf(mrun[r] - mnew[r]);
      rs[r] = 0.f;
    }
    #pragma unroll
    for (int nf = 0; nf < 4; ++nf)
      #pragma unroll
      for (int r = 0; r < 4; ++r) {
        float p = __expf(sf[nf][r] - mnew[r]);
        sf[nf][r] = p; rs[r] += p;
      }
    #pragma unroll
    for (int r = 0; r < 4; ++r) {
      #pragma unroll
      for (int off = 1; off < 16; off <<= 1) rs[r] += __shfl_xor(rs[r], off);
      lrun[r] = lrun[r]*scale[r] + rs[r];
      mrun[r] = mnew[r];
    }
    #pragma unroll
    for (int i = 0; i < 16; ++i) {
      oacc[i][0] *= scale[0]; oacc[i][1] *= scale[1];
      oacc[i][2] *= scale[2]; oacc[i][3] *= scale[3];
    }
    #pragma unroll
    for (int nf = 0; nf < 4; ++nf)
      #pragma unroll
      for (int r = 0; r < 4; ++r) {
        float pv = sf[nf][r];
        ushort ph, pl; split2(pv, ph, pl);
        uint mine = (uint)ph | ((uint)pl << 16);
        uint other = (uint)__shfl_xor((int)mine, 1);
        if ((l & 1) == 0) {
          int kv = nf*16 + l15, q = lq*4 + r;
          *(uint*)&pbh[w][kv>>3][q][kv&7] = (mine & 0xffffu) | ((other & 0xffffu) << 16);
          *(uint*)&pbl[w][kv>>3][q][kv&7] = (mine >> 16) | (other & 0xffff0000u);
        }
      }
    asm volatile("s_waitcnt lgkmcnt(0)" ::: "memory");
    __builtin_amdgcn_sched_barrier(0);
    #pragma unroll
    for (int k2 = 0; k2 < 2; ++k2) {
      int kc8 = k2*4 + lq;
      bf16x8 pfh = *(bf16x8*)&pbh[w][kc8][l15][0];
      bf16x8 pfl = *(bf16x8*)&pbl[w][kc8][l15][0];
      #pragma unroll
      for (int nf2 = 0; nf2 < 16; ++nf2) {
        int dl = nf2*16 + l15;
        bf16x8 vfh = *(bf16x8*)&vbh[kc8][dl ^ (kc8 & 7)][0];
        bf16x8 vfl = *(bf16x8*)&vbl[kc8][dl ^ (kc8 & 7)][0];
        oacc[nf2] = __builtin_amdgcn_mfma_f32_16x16x32_bf16(pfh, vfh, oacc[nf2], 0, 0, 0);
        oacc[nf2] = __builtin_amdgcn_mfma_f32_16x16x32_bf16(pfh, vfl, oacc[nf2], 0, 0, 0);
        oacc[nf2] = __builtin_amdgcn_mfma_f32_16x16x32_bf16(pfl, vfh, oacc[nf2], 0, 0, 0);
      }
    }
    __syncthreads();
  }
  #pragma unroll
  for (int r = 0; r < 4; ++r) {
    float inv = 1.f / lrun[r];
    int tok = qb + w*16 + lq*4 + r;
    #pragma unroll
    for (int nf2 = 0; nf2 < 16; ++nf2) {
      float o = oacc[nf2][r] * inv;
      ushort h2, l2; split2(o, h2, l2);
      ohi[(size_t)tok*Q_N + h*HD_ + nf2*16 + l15] = h2;
      olo[(size_t)tok*Q_N + h*HD_ + nf2*16 + l15] = l2;
    }
  }
}

// ---------------- O projection, split-bf16, K-sliced ----------------
__global__ __launch_bounds__(256, 2) void k_gemm_oproj(
    const ushort* __restrict__ Ah, const ushort* __restrict__ Al,
    const float* __restrict__ ow, float* __restrict__ Cp) {
  const int K = Q_N, KS = Q_N/2, NSs = KS/32;
  __shared__ ushort Ash[4][129][8], Asl[4][129][8];
  __shared__ ushort Bsh[4][65][8],  Bsl[4][65][8];
  int tid = threadIdx.x, w = tid >> 6, l = tid & 63;
  int n0 = blockIdx.x * 64, m0 = blockIdx.y * 128, kz = blockIdx.z;
  int kbase = kz * KS;
  float* C = Cp + (size_t)kz * T_S * H_DIM;
  const int l15 = l & 15, lq = l >> 4;
  const int wm = w >> 1, wn = w & 1;
  const int sar = tid >> 2, sak = tid & 3;
  const ushort* aph = Ah + (size_t)(m0 + sar)*K + kbase + sak*8;
  const ushort* apl = Al + (size_t)(m0 + sar)*K + kbase + sak*8;
  const float*  bp  = ow + (size_t)(n0 + sar)*K + kbase + sak*8;
  uint4 arh0 = *(const uint4*)(aph);
  uint4 arh1 = *(const uint4*)(aph + (size_t)64*K);
  uint4 arl0 = *(const uint4*)(apl);
  uint4 arl1 = *(const uint4*)(apl + (size_t)64*K);
  float4 brA = *(const float4*)(bp), brB = *(const float4*)(bp + 4);
  f32x4 acc[4][2];
  #pragma unroll
  for (int a = 0; a < 4; ++a)
    #pragma unroll
    for (int b = 0; b < 2; ++b) acc[a][b] = (f32x4){0.f,0.f,0.f,0.f};
  for (int t = 0; t < NSs; ++t) {
    *(uint4*)&Ash[sak][sar][0]    = arh0;
    *(uint4*)&Ash[sak][64+sar][0] = arh1;
    *(uint4*)&Asl[sak][sar][0]    = arl0;
    *(uint4*)&Asl[sak][64+sar][0] = arl1;
    { uint4 H, L; split8(brA, brB, H, L);
      *(uint4*)&Bsh[sak][sar][0] = H;
      *(uint4*)&Bsl[sak][sar][0] = L; }
    __syncthreads();
    if (t + 1 < NSs) {
      int k0 = (t+1)*32;
      arh0 = *(const uint4*)(aph + k0);
      arh1 = *(const uint4*)(aph + (size_t)64*K + k0);
      arl0 = *(const uint4*)(apl + k0);
      arl1 = *(const uint4*)(apl + (size_t)64*K + k0);
      brA = *(const float4*)(bp + k0); brB = *(const float4*)(bp + k0 + 4);
    }
    bf16x8 bh[2], bl[2];
    #pragma unroll
    for (int nf = 0; nf < 2; ++nf) {
      bh[nf] = *(bf16x8*)&Bsh[lq][wn*32 + nf*16 + l15][0];
      bl[nf] = *(bf16x8*)&Bsl[lq][wn*32 + nf*16 + l15][0];
    }
    #pragma unroll
    for (int mf = 0; mf < 4; ++mf) {
      bf16x8 ah = *(bf16x8*)&Ash[lq][wm*64 + mf*16 + l15][0];
      bf16x8 al = *(bf16x8*)&Asl[lq][wm*64 + mf*16 + l15][0];
      #pragma unroll
      for (int nf = 0; nf < 2; ++nf) {
        acc[mf][nf] = __builtin_amdgcn_mfma_f32_16x16x32_bf16(ah, bh[nf], acc[mf][nf], 0, 0, 0);
        acc[mf][nf] = __builtin_amdgcn_mfma_f32_16x16x32_bf16(ah, bl[nf], acc[mf][nf], 0, 0, 0);
        acc[mf][nf] = __builtin_amdgcn_mfma_f32_16x16x32_bf16(al, bh[nf], acc[mf][nf], 0, 0, 0);
      }
    }
    __syncthreads();
  }
  #pragma unroll
  for (int mf = 0; mf < 4; ++mf)
    #pragma unroll
    for (int nf = 0; nf < 2; ++nf)
      #pragma unroll
      for (int r = 0; r < 4; ++r)
        C[(size_t)(m0 + wm*64 + mf*16 + lq*4 + r)*H_DIM + n0 + wn*32 + nf*16 + l15] = acc[mf][nf][r];
}

__global__ void k_zero_counts(int* counts) {
  if (threadIdx.x < N_E) counts[threadIdx.x] = 0;
}

// ---------------- post-attn + residual + pre-ffn + router (fp32, sums 2 K-slices) ----------------
__global__ __launch_bounds__(256) void k_fuse_router(
    const float* __restrict__ hid, const float* __restrict__ aproj0,
    const float* __restrict__ aproj1,
    const float* __restrict__ w_pa, const float* __restrict__ w_pf,
    const float* __restrict__ rscale, const float* __restrict__ rw,
    float* __restrict__ xout, ushort* __restrict__ tbf,
    float* __restrict__ topw, int* __restrict__ counts, int* __restrict__ lists) {
  __shared__ float sm[4];
  __shared__ float nrow[H_DIM];
  __shared__ float lg[N_E];
  int t = blockIdx.x, tid = threadIdx.x;
  float ap[11], hd[11]; float s = 0.f;
  #pragma unroll
  for (int j = 0; j < 11; ++j) {
    int idx = tid + j*256;
    ap[j] = aproj0[(size_t)t*H_DIM + idx] + aproj1[(size_t)t*H_DIM + idx];
    hd[j] = hid[(size_t)t*H_DIM + idx];
    s += ap[j]*ap[j];
  }
  s = block_sum256(s, sm);
  float r1 = rsqrtf(s / (float)H_DIM + EPS_);
  float x[11]; float s2 = 0.f;
  #pragma unroll
  for (int j = 0; j < 11; ++j) {
    int idx = tid + j*256;
    x[j] = hd[j] + ap[j]*r1*w_pa[idx];
    s2 += x[j]*x[j];
    xout[(size_t)t*H_DIM + idx] = x[j];
  }
  s2 = block_sum256(s2, sm);
  float r2 = rsqrtf(s2 / (float)H_DIM + EPS_);
  float tv[11]; float s3 = 0.f;
  #pragma unroll
  for (int j = 0; j < 11; ++j) {
    int idx = tid + j*256;
    tv[j] = x[j]*r2*w_pf[idx];
    s3 += tv[j]*tv[j];
    tbf[(size_t)t*H_DIM + idx] = f2bf(tv[j]);
  }
  s3 = block_sum256(s3, sm);
  float r3 = rsqrtf(s3 / (float)H_DIM + EPS_) * rsqrtf((float)H_DIM);
  #pragma unroll
  for (int j = 0; j < 11; ++j) {
    int idx = tid + j*256;
    nrow[idx] = tv[j]*r3*rscale[idx];
  }
  __syncthreads();
  int w = tid >> 6, l = tid & 63;
  #pragma unroll
  for (int ei = 0; ei < 8; ++ei) {
    int e = w*8 + ei;
    const float* rwp = rw + (size_t)e*H_DIM;
    float p = 0.f;
    #pragma unroll 4
    for (int j = 0; j < 44; ++j) p += nrow[l + j*64] * rwp[l + j*64];
    p = wave_sum(p);
    if (l == 0) lg[e] = p;
  }
  __syncthreads();
  if (w == 0) {
    float le = (l < 32) ? lg[l] : -3e38f;
    float m = le;
    #pragma unroll
    for (int off = 1; off < 64; off <<= 1) m = fmaxf(m, __shfl_xor(m, off));
    float p = (l < 32) ? __expf(le - m) : -2.f;
    float v = p; int vi = (l < 32) ? l : 999;
    float selv[TOPK_]; int seli[TOPK_];
    for (int sx = 0; sx < TOPK_; ++sx) {
      float bv = v; int bi = vi;
      #pragma unroll
      for (int off = 1; off < 64; off <<= 1) {
        float ov = __shfl_xor(bv, off); int oi = __shfl_xor(bi, off);
        if (ov > bv || (ov == bv && oi < bi)) { bv = ov; bi = oi; }
      }
      selv[sx] = bv; seli[sx] = bi;
      if (vi == bi) v = -1.f;
    }
    if (l == 0) {
      float wsum = selv[0]+selv[1]+selv[2]+selv[3];
      for (int sx = 0; sx < TOPK_; ++sx) {
        topw[t*TOPK_ + sx] = selv[sx]/wsum;
        int e = seli[sx];
        int pos = atomicAdd(&counts[e], 1);
        lists[e*T_S + pos] = t*TOPK_ + sx;
      }
    }
  }
}

// ---------------- MoE stage 1: M=128, N=64(g+u), K-split 4 -> fp32 partials ----------------
// grid (11, 32, 16); XCD-swizzled block remap (nwg=5632=8*704)
__global__ __launch_bounds__(256, 2) void k_moe_gateup(
    const ushort* __restrict__ tbf, const float* __restrict__ wg,
    const float* __restrict__ wu, const int* __restrict__ counts,
    const int* __restrict__ lists, float* __restrict__ pg, float* __restrict__ pu) {
  const int K = H_DIM, KS = K/4, NS = KS/32;   // 704, 22
  __shared__ ushort As[4][129][8];
  __shared__ ushort Bg[4][65][8], Bu[4][65][8];
  __shared__ int lls[128];
  int tid = threadIdx.x, w = tid >> 6, l = tid & 63;
  // XCD-aware bijective swizzle: phys round-robins XCDs; give each XCD a
  // contiguous run of logical blocks so A/B-sharing groups stay L2-local.
  int phys = blockIdx.x + 11*(blockIdx.y + 32*blockIdx.z);
  int logi = (phys & 7) * 704 + (phys >> 3);
  int bx = logi % 11;
  int rem = logi / 11;
  int e = rem & 31, bz = rem >> 5;
  int n0 = bx * 64;
  int mz = bz >> 2, kz = bz & 3;
  int m0 = mz * 128, kbase = kz * KS;
  int ne = counts[e];
  if (m0 >= ne) return;
  const int* list = lists + e*T_S;
  if (tid < 128) lls[tid] = (m0 + tid < ne) ? list[m0 + tid] : list[0];
  __syncthreads();
  const int l15 = l & 15, lq = l >> 4;
  const int wm = w >> 1, wn = w & 1;
  const int arow = tid >> 1, aoct = (tid & 1) * 2;
  const ushort* ap = tbf + (size_t)(lls[arow] >> 2)*K + kbase + aoct*8;
  const int bhalf = tid >> 7, brow = (tid & 127) >> 1, boct = (tid & 1) * 2;
  const float* bp = (bhalf ? wu : wg) + ((size_t)e*I_DIM + n0 + brow)*K + kbase + boct*8;
  uint4 a0 = *(const uint4*)(ap), a1 = *(const uint4*)(ap + 8);
  float4 b0 = *(const float4*)(bp),     b1 = *(const float4*)(bp + 4);
  float4 b2 = *(const float4*)(bp + 8), b3 = *(const float4*)(bp + 12);
  f32x4 ag[4][2], au[4][2];
  #pragma unroll
  for (int a = 0; a < 4; ++a)
    #pragma unroll
    for (int b = 0; b < 2; ++b) { ag[a][b] = (f32x4){0.f,0.f,0.f,0.f}; au[a][b] = (f32x4){0.f,0.f,0.f,0.f}; }
  for (int t = 0; t < NS; ++t) {
    *(uint4*)&As[aoct][arow][0]   = a0;
    *(uint4*)&As[aoct+1][arow][0] = a1;
    if (bhalf == 0) {
      *(uint4*)&Bg[boct][brow][0]   = pack8(b0, b1);
      *(uint4*)&Bg[boct+1][brow][0] = pack8(b2, b3);
    } else {
      *(uint4*)&Bu[boct][brow][0]   = pack8(b0, b1);
      *(uint4*)&Bu[boct+1][brow][0] = pack8(b2, b3);
    }
    __syncthreads();
    if (t + 1 < NS) {
      int k0 = (t+1)*32;
      a0 = *(const uint4*)(ap + k0); a1 = *(const uint4*)(ap + k0 + 8);
      b0 = *(const float4*)(bp + k0);     b1 = *(const float4*)(bp + k0 + 4);
      b2 = *(const float4*)(bp + k0 + 8); b3 = *(const float4*)(bp + k0 + 12);
    }
    bf16x8 bgf[2], buf_[2];
    #pragma unroll
    for (int nf = 0; nf < 2; ++nf) {
      bgf[nf]  = *(bf16x8*)&Bg[lq][wn*32 + nf*16 + l15][0];
      buf_[nf] = *(bf16x8*)&Bu[lq][wn*32 + nf*16 + l15][0];
    }
    #pragma unroll
    for (int mf = 0; mf < 4; ++mf) {
      bf16x8 af = *(bf16x8*)&As[lq][wm*64 + mf*16 + l15][0];
      #pragma unroll
      for (int nf = 0; nf < 2; ++nf) {
        ag[mf][nf] = __builtin_amdgcn_mfma_f32_16x16x32_bf16(af, bgf[nf],  ag[mf][nf], 0, 0, 0);
        au[mf][nf] = __builtin_amdgcn_mfma_f32_16x16x32_bf16(af, buf_[nf], au[mf][nf], 0, 0, 0);
      }
    }
    __syncthreads();
  }
  const size_t PSL = (size_t)NSLOT * I_DIM;
  #pragma unroll
  for (int mf = 0; mf < 4; ++mf)
    #pragma unroll
    for (int r = 0; r < 4; ++r) {
      int row = wm*64 + mf*16 + lq*4 + r;
      if (m0 + row < ne) {
        size_t base = (size_t)kz*PSL + (size_t)lls[row]*I_DIM + n0 + wn*32;
        #pragma unroll
        for (int nf = 0; nf < 2; ++nf) {
          pg[base + nf*16 + l15] = ag[mf][nf][r];
          pu[base + nf*16 + l15] = au[mf][nf][r];
        }
      }
    }
}

// ---------------- gelu-reduce: sum 4 K-slices, gelu(g)*u -> bf16 abf ----------------
__global__ __launch_bounds__(192) void k_gelu_reduce(
    const float* __restrict__ pg, const float* __restrict__ pu,
    ushort* __restrict__ abf) {
  int sidx = blockIdx.x, c = threadIdx.x;
  if (c >= 176) return;
  const size_t S4 = (size_t)NSLOT * I_DIM / 4;
  const float4* g = (const float4*)(pg + (size_t)sidx*I_DIM) + c;
  const float4* u = (const float4*)(pu + (size_t)sidx*I_DIM) + c;
  float4 gs = g[0], us = u[0];
  #pragma unroll
  for (int k = 1; k < 4; ++k) {
    float4 gk = g[k*S4], uk = u[k*S4];
    gs.x += gk.x; gs.y += gk.y; gs.z += gk.z; gs.w += gk.w;
    us.x += uk.x; us.y += uk.y; us.z += uk.z; us.w += uk.w;
  }
  float go[4] = {gs.x, gs.y, gs.z, gs.w}, uo[4] = {us.x, us.y, us.z, us.w};
  ushort o[4];
  #pragma unroll
  for (int i = 0; i < 4; ++i) {
    float gg = go[i];
    float th = tanhf(0.7978845608f*(gg + 0.044715f*gg*gg*gg));
    o[i] = f2bf(0.5f*gg*(1.f + th)*uo[i]);
  }
  *(ushort4*)(abf + (size_t)sidx*I_DIM + c*4) = *(ushort4*)o;
}

// ---------------- MoE stage 2: M=128, N=128, K-split 2 -> fp32 partials ----------------
// grid (22, 32, 8); XCD-swizzled block remap (nwg=5632=8*704)
__global__ __launch_bounds__(256, 2) void k_moe_down(
    const ushort* __restrict__ abf, const float* __restrict__ wd,
    const int* __restrict__ counts, const int* __restrict__ lists,
    float* __restrict__ yp) {
  const int K = I_DIM, KS = K/2, NS = KS/32;   // 352, 11
  __shared__ ushort As[4][129][8];
  __shared__ ushort Bs[4][129][8];
  __shared__ int lls[128];
  int tid = threadIdx.x, w = tid >> 6, l = tid & 63;
  int phys = blockIdx.x + 22*(blockIdx.y + 32*blockIdx.z);
  int logi = (phys & 7) * 704 + (phys >> 3);
  int bx = logi % 22;
  int rem = logi / 22;
  int e = rem & 31, bz = rem >> 5;
  int n0 = bx * 128;
  int mz = bz >> 1, kz = bz & 1;
  int m0 = mz * 128, kbase = kz * KS;
  int ne = counts[e];
  if (m0 >= ne) return;
  const int* list = lists + e*T_S;
  if (tid < 128) lls[tid] = (m0 + tid < ne) ? list[m0 + tid] : 0;
  __syncthreads();
  const int l15 = l & 15, lq = l >> 4;
  const int wm = w >> 1, wn = w & 1;
  const int arow = tid >> 1, aoct = (tid & 1) * 2;
  const ushort* ap = abf + (size_t)lls[arow]*K + kbase + aoct*8;
  const int brow = tid >> 1, boct = (tid & 1) * 2;
  const float* bp = wd + ((size_t)e*H_DIM + n0 + brow)*K + kbase + boct*8;
  uint4 a0 = *(const uint4*)(ap), a1 = *(const uint4*)(ap + 8);
  float4 b0 = *(const float4*)(bp),     b1 = *(const float4*)(bp + 4);
  float4 b2 = *(const float4*)(bp + 8), b3 = *(const float4*)(bp + 12);
  f32x4 acc[4][4];
  #pragma unroll
  for (int a = 0; a < 4; ++a)
    #pragma unroll
    for (int b = 0; b < 4; ++b) acc[a][b] = (f32x4){0.f,0.f,0.f,0.f};
  for (int t = 0; t < NS; ++t) {
    *(uint4*)&As[aoct][arow][0]   = a0;
    *(uint4*)&As[aoct+1][arow][0] = a1;
    *(uint4*)&Bs[boct][brow][0]   = pack8(b0, b1);
    *(uint4*)&Bs[boct+1][brow][0] = pack8(b2, b3);
    __syncthreads();
    if (t + 1 < NS) {
      int k0 = (t+1)*32;
      a0 = *(const uint4*)(ap + k0); a1 = *(const uint4*)(ap + k0 + 8);
      b0 = *(const float4*)(bp + k0);     b1 = *(const float4*)(bp + k0 + 4);
      b2 = *(const float4*)(bp + k0 + 8); b3 = *(const float4*)(bp + k0 + 12);
    }
    bf16x8 bf[4];
    #pragma unroll
    for (int nf = 0; nf < 4; ++nf)
      bf[nf] = *(bf16x8*)&Bs[lq][wn*64 + nf*16 + l15][0];
    #pragma unroll
    for (int mf = 0; mf < 4; ++mf) {
      bf16x8 af = *(bf16x8*)&As[lq][wm*64 + mf*16 + l15][0];
      #pragma unroll
      for (int nf = 0; nf < 4; ++nf)
        acc[mf][nf] = __builtin_amdgcn_mfma_f32_16x16x32_bf16(af, bf[nf], acc[mf][nf], 0, 0, 0);
    }
    __syncthreads();
  }
  const size_t YSL = (size_t)NSLOT * H_DIM;
  #pragma unroll
  for (int mf = 0; mf < 4; ++mf)
    #pragma unroll
    for (int r = 0; r < 4; ++r) {
      int row = wm*64 + mf*16 + lq*4 + r;
      if (m0 + row < ne) {
        size_t base = (size_t)kz*YSL + (size_t)lls[row]*H_DIM + n0 + wn*64;
        #pragma unroll
        for (int nf = 0; nf < 4; ++nf)
          yp[base + nf*16 + l15] = acc[mf][nf][r];
      }
    }
}

// ---------------- combine (sums 2 down K-slices) + post-ffn rmsnorm + residual ----------------
__global__ __launch_bounds__(256) void k_combine(
    const float* __restrict__ yp, const float* __restrict__ topw,
    const float* __restrict__ xin, const float* __restrict__ w_pff,
    float* __restrict__ out) {
  __shared__ float sm[4];
  const size_t YSL = (size_t)NSLOT * H_DIM;
  int t = blockIdx.x, tid = threadIdx.x;
  float w0 = topw[t*4+0], w1 = topw[t*4+1], w2 = topw[t*4+2], w3 = topw[t*4+3];
  const float* y0 = yp + (size_t)(t*4+0)*H_DIM;
  const float* y1 = yp + (size_t)(t*4+1)*H_DIM;
  const float* y2 = yp + (size_t)(t*4+2)*H_DIM;
  const float* y3 = yp + (size_t)(t*4+3)*H_DIM;
  float m[11]; float s = 0.f;
  #pragma unroll
  for (int j = 0; j < 11; ++j) {
    int idx = tid + j*256;
    m[j] = w0*(y0[idx]+y0[YSL+idx]) + w1*(y1[idx]+y1[YSL+idx])
         + w2*(y2[idx]+y2[YSL+idx]) + w3*(y3[idx]+y3[YSL+idx]);
    s += m[j]*m[j];
  }
  s = block_sum256(s, sm);
  float r = rsqrtf(s / (float)H_DIM + EPS_);
  #pragma unroll
  for (int j = 0; j < 11; ++j) {
    int idx = tid + j*256;
    out[(size_t)t*H_DIM + idx] = xin[(size_t)t*H_DIM + idx] + m[j]*r*w_pff[idx];
  }
}

extern "C" void kernel_launch(void* const* d_in, const int* in_sizes, int n_in,
                              void* d_out, int out_size, void* d_ws, size_t ws_size,
                              hipStream_t stream) {
  (void)in_sizes; (void)n_in; (void)out_size; (void)ws_size;
  const float* hid   = (const float*)d_in[0];
  const float* cosb  = (const float*)d_in[1];
  const float* sinb  = (const float*)d_in[2];
  const float* w_in  = (const float*)d_in[3];
  const float* w_pa  = (const float*)d_in[4];
  const float* w_pf  = (const float*)d_in[5];
  const float* w_pff = (const float*)d_in[6];
  const float* qw    = (const float*)d_in[7];
  const float* kw    = (const float*)d_in[8];
  const float* vw    = (const float*)d_in[9];
  const float* ow    = (const float*)d_in[10];
  const float* qnw   = (const float*)d_in[11];
  const float* knw   = (const float*)d_in[12];
  const float* rw    = (const float*)d_in[13];
  const float* rsc   = (const float*)d_in[14];
  const float* wg    = (const float*)d_in[15];
  const float* wu    = (const float*)d_in[16];
  const float* wd    = (const float*)d_in[17];

  char* ws = (char*)d_ws;
  size_t off = 0;
  auto alloc = [&](size_t sz) { size_t o = off; off += (sz + 255) & ~(size_t)255; return o; };
  size_t oR1  = alloc(46137344);
  size_t ohh  = alloc((size_t)T_S*H_DIM*2);
  size_t ohl  = alloc((size_t)T_S*H_DIM*2);
  size_t oqh  = alloc((size_t)T_S*QKV_N*2);
  size_t oql  = alloc((size_t)T_S*QKV_N*2);
  size_t ovh  = alloc((size_t)8*HD_*T_S*2);
  size_t ovl  = alloc((size_t)8*HD_*T_S*2);
  size_t ox   = alloc((size_t)T_S*H_DIM*4);
  size_t otbf = alloc((size_t)T_S*H_DIM*2);
  size_t otw  = alloc((size_t)T_S*TOPK_*4);
  size_t ocnt = alloc((size_t)N_E*4);
  size_t olst = alloc((size_t)N_E*T_S*4);

  const size_t APRJ_SLICE = (size_t)T_S * H_DIM * 4;

  float*  qkvf0 = (float*)(ws + oR1);
  float*  qkvf1 = (float*)(ws + oR1 + 16777216);
  ushort* o_hi  = (ushort*)(ws + oR1);
  ushort* o_lo  = (ushort*)(ws + oR1 + 4194304);
  float*  aprj0 = (float*)(ws + oR1 + 8388608);
  float*  aprj1 = (float*)(ws + oR1 + 8388608 + APRJ_SLICE);
  float*  pg    = (float*)(ws + oR1);
  float*  pu    = (float*)(ws + oR1 + 23068672);
  float*  yp    = (float*)(ws + oR1);
  ushort* abf   = (ushort*)(ws + ohh);

  k_ln_in<<<dim3(T_S), dim3(256), 0, stream>>>(hid, w_in, (ushort*)(ws+ohh), (ushort*)(ws+ohl));
  k_gemm_qkv<<<dim3(128, 4, 2), dim3(256), 0, stream>>>((ushort*)(ws+ohh), (ushort*)(ws+ohl),
                                                        qw, kw, vw, qkvf0);
  k_norm_rope<<<dim3(T_S*32), dim3(64), 0, stream>>>(qkvf0, qkvf1, cosb, sinb, qnw, knw,
                                                     (ushort*)(ws+oqh), (ushort*)(ws+oql),
                                                     (ushort*)(ws+ovh), (ushort*)(ws+ovl));
  k_attn<<<dim3(8, 16), dim3(256), 0, stream>>>((ushort*)(ws+oqh), (ushort*)(ws+oql),
                                                (ushort*)(ws+ovh), (ushort*)(ws+ovl), o_hi, o_lo);
  k_gemm_oproj<<<dim3(44, 4, 2), dim3(256), 0, stream>>>(o_hi, o_lo, ow, aprj0);
  k_zero_counts<<<dim3(1), dim3(64), 0, stream>>>((int*)(ws+ocnt));
  k_fuse_router<<<dim3(T_S), dim3(256), 0, stream>>>(hid, aprj0, aprj1, w_pa, w_pf, rsc, rw,
                                                     (float*)(ws+ox), (ushort*)(ws+otbf),
                                                     (float*)(ws+otw), (int*)(ws+ocnt), (int*)(ws+olst));
  k_moe_gateup<<<dim3(11, N_E, 16), dim3(256), 0, stream>>>((ushort*)(ws+otbf), wg, wu,
                                                            (int*)(ws+ocnt), (int*)(ws+olst), pg, pu);
  k_gelu_reduce<<<dim3(NSLOT), dim3(192), 0, stream>>>(pg, pu, abf);
  k_moe_down<<<dim3(22, N_E, 8), dim3(256), 0, stream>>>(abf, wd,
                                                         (int*)(ws+ocnt), (int*)(ws+olst), yp);
  k_combine<<<dim3(T_S), dim3(256), 0, stream>>>(yp, (float*)(ws+otw), (float*)(ws+ox),
                                                 w_pff, (float*)d_out);
}

// Round 14
// 608.243 us; speedup vs baseline: 1.5757x; 1.5757x over previous
//
#include <hip/hip_runtime.h>

static constexpr int T_S   = 512;
static constexpr int H_DIM = 2816;
static constexpr int HD_   = 256;
static constexpr int N_E   = 32;
static constexpr int TOPK_ = 4;
static constexpr int I_DIM = 704;
static constexpr int Q_N   = 4096;
static constexpr int KV_N  = 2048;
static constexpr int QKV_N = 8192;
static constexpr int NSLOT = 2048;               // T_S * TOPK_
static constexpr float EPS_ = 1e-6f;

typedef __attribute__((ext_vector_type(4))) float f32x4;
typedef __attribute__((ext_vector_type(8))) short bf16x8;

static __device__ __forceinline__ ushort f2bf(float f) {
  uint u = __float_as_uint(f);
  u += 0x7fffu + ((u >> 16) & 1u);
  return (ushort)(u >> 16);
}
static __device__ __forceinline__ float bf2f(ushort u) {
  return __uint_as_float((uint)u << 16);
}
static __device__ __forceinline__ void split2(float x, ushort& h, ushort& l2) {
  h = f2bf(x);
  l2 = f2bf(x - bf2f(h));
}
static __device__ __forceinline__ void split8(const float4& a, const float4& b,
                                              uint4& H, uint4& L) {
  ushort h0,l0,h1,l1,h2,l2,h3,l3,h4,l4,h5,l5,h6,l6,h7,l7;
  split2(a.x,h0,l0); split2(a.y,h1,l1); split2(a.z,h2,l2); split2(a.w,h3,l3);
  split2(b.x,h4,l4); split2(b.y,h5,l5); split2(b.z,h6,l6); split2(b.w,h7,l7);
  H = (uint4){ (uint)h0|((uint)h1<<16), (uint)h2|((uint)h3<<16),
               (uint)h4|((uint)h5<<16), (uint)h6|((uint)h7<<16) };
  L = (uint4){ (uint)l0|((uint)l1<<16), (uint)l2|((uint)l3<<16),
               (uint)l4|((uint)l5<<16), (uint)l6|((uint)l7<<16) };
}
static __device__ __forceinline__ uint4 pack8(const float4& a, const float4& b) {
  return (uint4){ (uint)f2bf(a.x)|((uint)f2bf(a.y)<<16), (uint)f2bf(a.z)|((uint)f2bf(a.w)<<16),
                  (uint)f2bf(b.x)|((uint)f2bf(b.y)<<16), (uint)f2bf(b.z)|((uint)f2bf(b.w)<<16) };
}
static __device__ __forceinline__ ushort4 pack4(const float4& a) {
  return (ushort4){ f2bf(a.x), f2bf(a.y), f2bf(a.z), f2bf(a.w) };
}

static __device__ __forceinline__ float wave_sum(float v) {
  #pragma unroll
  for (int off = 1; off < 64; off <<= 1) v += __shfl_xor(v, off);
  return v;
}
static __device__ __forceinline__ float block_sum256(float v, float* sm) {
  v = wave_sum(v);
  int w = threadIdx.x >> 6, l = threadIdx.x & 63;
  if (l == 0) sm[w] = v;
  __syncthreads();
  float r = sm[0] + sm[1] + sm[2] + sm[3];
  __syncthreads();
  return r;
}

// ---------------- input RMSNorm -> bf16 hi/lo ----------------
__global__ __launch_bounds__(256) void k_ln_in(
    const float* __restrict__ hid, const float* __restrict__ w,
    ushort* __restrict__ hhi, ushort* __restrict__ hlo) {
  __shared__ float sm[4];
  int t = blockIdx.x, tid = threadIdx.x;
  const float* row = hid + (size_t)t * H_DIM;
  float x[11]; float s = 0.f;
  #pragma unroll
  for (int j = 0; j < 11; ++j) { x[j] = row[tid + j*256]; s += x[j]*x[j]; }
  s = block_sum256(s, sm);
  float r = rsqrtf(s / (float)H_DIM + EPS_);
  #pragma unroll
  for (int j = 0; j < 11; ++j) {
    int idx = tid + j*256;
    float val = x[j]*r*w[idx];
    ushort h, l2; split2(val, h, l2);
    hhi[(size_t)t*H_DIM + idx] = h;
    hlo[(size_t)t*H_DIM + idx] = l2;
  }
}

// ---------------- QKV GEMM, split-bf16, K-sliced ----------------
__global__ __launch_bounds__(256, 2) void k_gemm_qkv(
    const ushort* __restrict__ Ah, const ushort* __restrict__ Al,
    const float* __restrict__ qw, const float* __restrict__ kw,
    const float* __restrict__ vw, float* __restrict__ Cp) {
  const int K = H_DIM, KS = H_DIM/2, NSs = KS/32;
  __shared__ ushort Ash[4][129][8], Asl[4][129][8];
  __shared__ ushort Bsh[4][65][8],  Bsl[4][65][8];
  int tid = threadIdx.x, w = tid >> 6, l = tid & 63;
  int n0 = blockIdx.x * 64, m0 = blockIdx.y * 128, kz = blockIdx.z;
  int kbase = kz * KS;
  const float* Bp = (n0 < Q_N) ? qw + (size_t)n0*K
                  : (n0 < Q_N+KV_N) ? kw + (size_t)(n0-Q_N)*K
                  : vw + (size_t)(n0-Q_N-KV_N)*K;
  float* C = Cp + (size_t)kz * T_S * QKV_N;
  const int l15 = l & 15, lq = l >> 4;
  const int wm = w >> 1, wn = w & 1;
  const int sar = tid >> 2, sak = tid & 3;
  const ushort* aph = Ah + (size_t)(m0 + sar)*K + kbase + sak*8;
  const ushort* apl = Al + (size_t)(m0 + sar)*K + kbase + sak*8;
  const float*  bp  = Bp + (size_t)sar*K + kbase + sak*8;
  uint4 arh0 = *(const uint4*)(aph);
  uint4 arh1 = *(const uint4*)(aph + (size_t)64*K);
  uint4 arl0 = *(const uint4*)(apl);
  uint4 arl1 = *(const uint4*)(apl + (size_t)64*K);
  float4 brA = *(const float4*)(bp), brB = *(const float4*)(bp + 4);
  f32x4 acc[4][2];
  #pragma unroll
  for (int a = 0; a < 4; ++a)
    #pragma unroll
    for (int b = 0; b < 2; ++b) acc[a][b] = (f32x4){0.f,0.f,0.f,0.f};
  for (int t = 0; t < NSs; ++t) {
    *(uint4*)&Ash[sak][sar][0]    = arh0;
    *(uint4*)&Ash[sak][64+sar][0] = arh1;
    *(uint4*)&Asl[sak][sar][0]    = arl0;
    *(uint4*)&Asl[sak][64+sar][0] = arl1;
    { uint4 H, L; split8(brA, brB, H, L);
      *(uint4*)&Bsh[sak][sar][0] = H;
      *(uint4*)&Bsl[sak][sar][0] = L; }
    __syncthreads();
    if (t + 1 < NSs) {
      int k0 = (t+1)*32;
      arh0 = *(const uint4*)(aph + k0);
      arh1 = *(const uint4*)(aph + (size_t)64*K + k0);
      arl0 = *(const uint4*)(apl + k0);
      arl1 = *(const uint4*)(apl + (size_t)64*K + k0);
      brA = *(const float4*)(bp + k0); brB = *(const float4*)(bp + k0 + 4);
    }
    bf16x8 bh[2], bl[2];
    #pragma unroll
    for (int nf = 0; nf < 2; ++nf) {
      bh[nf] = *(bf16x8*)&Bsh[lq][wn*32 + nf*16 + l15][0];
      bl[nf] = *(bf16x8*)&Bsl[lq][wn*32 + nf*16 + l15][0];
    }
    #pragma unroll
    for (int mf = 0; mf < 4; ++mf) {
      bf16x8 ah = *(bf16x8*)&Ash[lq][wm*64 + mf*16 + l15][0];
      bf16x8 al = *(bf16x8*)&Asl[lq][wm*64 + mf*16 + l15][0];
      #pragma unroll
      for (int nf = 0; nf < 2; ++nf) {
        acc[mf][nf] = __builtin_amdgcn_mfma_f32_16x16x32_bf16(ah, bh[nf], acc[mf][nf], 0, 0, 0);
        acc[mf][nf] = __builtin_amdgcn_mfma_f32_16x16x32_bf16(ah, bl[nf], acc[mf][nf], 0, 0, 0);
        acc[mf][nf] = __builtin_amdgcn_mfma_f32_16x16x32_bf16(al, bh[nf], acc[mf][nf], 0, 0, 0);
      }
    }
    __syncthreads();
  }
  #pragma unroll
  for (int mf = 0; mf < 4; ++mf)
    #pragma unroll
    for (int nf = 0; nf < 2; ++nf)
      #pragma unroll
      for (int r = 0; r < 4; ++r)
        C[(size_t)(m0 + wm*64 + mf*16 + lq*4 + r)*QKV_N + n0 + wn*32 + nf*16 + l15] = acc[mf][nf][r];
}

// ---------------- per-(token,head) norm + RoPE (sums 2 K-slices) ----------------
__global__ __launch_bounds__(64) void k_norm_rope(
    const float* __restrict__ qkvf0, const float* __restrict__ qkvf1,
    const float* __restrict__ cosb, const float* __restrict__ sinb,
    const float* __restrict__ qnw, const float* __restrict__ knw,
    ushort* __restrict__ qh, ushort* __restrict__ ql,
    ushort* __restrict__ vth, ushort* __restrict__ vtl) {
  int bid = blockIdx.x;
  int token = bid >> 5, ch = bid & 31;
  int l = threadIdx.x;
  int col; const float* wp = nullptr; bool rope = true; int vch = -1;
  if (ch < 16)      { col = ch*HD_; wp = qnw; }
  else if (ch < 24) { col = Q_N + (ch-16)*HD_; wp = knw; }
  else              { col = Q_N + KV_N + (ch-24)*HD_; rope = false; vch = ch-24; }
  size_t base = (size_t)token*QKV_N + col;
  float4 va = *(const float4*)(qkvf0 + base + l*4);
  float4 vb = *(const float4*)(qkvf1 + base + l*4);
  float4 v = { va.x+vb.x, va.y+vb.y, va.z+vb.z, va.w+vb.w };
  float s = v.x*v.x + v.y*v.y + v.z*v.z + v.w*v.w;
  s = wave_sum(s);
  float r = rsqrtf(s / (float)HD_ + EPS_);
  float n0 = v.x*r, n1 = v.y*r, n2 = v.z*r, n3 = v.w*r;
  if (wp) { float4 w4 = *(const float4*)(wp + l*4); n0*=w4.x; n1*=w4.y; n2*=w4.z; n3*=w4.w; }
  float o0 = n0, o1 = n1, o2 = n2, o3 = n3;
  if (rope) {
    float p0 = __shfl_xor(n0, 32), p1 = __shfl_xor(n1, 32),
          p2 = __shfl_xor(n2, 32), p3 = __shfl_xor(n3, 32);
    float sg = (l < 32) ? -1.f : 1.f;
    float4 c4 = *(const float4*)(cosb + (size_t)token*HD_ + l*4);
    float4 s4 = *(const float4*)(sinb + (size_t)token*HD_ + l*4);
    o0 = n0*c4.x + sg*p0*s4.x;
    o1 = n1*c4.y + sg*p1*s4.y;
    o2 = n2*c4.z + sg*p2*s4.z;
    o3 = n3*c4.w + sg*p3*s4.w;
  }
  ushort h0,e0,h1,e1,h2,e2,h3,e3;
  split2(o0,h0,e0); split2(o1,h1,e1); split2(o2,h2,e2); split2(o3,h3,e3);
  ushort4 pkh = {h0,h1,h2,h3}, pkl = {e0,e1,e2,e3};
  *(ushort4*)(qh + base + l*4) = pkh;
  *(ushort4*)(ql + base + l*4) = pkl;
  if (vch >= 0) {
    size_t vb2 = ((size_t)vch*HD_)*T_S + token;
    vth[vb2 + (size_t)(l*4+0)*T_S] = pkh.x; vth[vb2 + (size_t)(l*4+1)*T_S] = pkh.y;
    vth[vb2 + (size_t)(l*4+2)*T_S] = pkh.z; vth[vb2 + (size_t)(l*4+3)*T_S] = pkh.w;
    vtl[vb2 + (size_t)(l*4+0)*T_S] = pkl.x; vtl[vb2 + (size_t)(l*4+1)*T_S] = pkl.y;
    vtl[vb2 + (size_t)(l*4+2)*T_S] = pkl.z; vtl[vb2 + (size_t)(l*4+3)*T_S] = pkl.w;
  }
}

// ---------------- flash attention (causal, no scale, GQA 2:1), split-bf16 ----------------
__global__ __launch_bounds__(256, 1) void k_attn(
    const ushort* __restrict__ qbh, const ushort* __restrict__ qbl,
    const ushort* __restrict__ vth, const ushort* __restrict__ vtl,
    ushort* __restrict__ ohi, ushort* __restrict__ olo) {
  __shared__ ushort kbh[32][64][8], kbl[32][64][8];
  __shared__ ushort vbh[8][256][8], vbl[8][256][8];
  __shared__ ushort pbh[4][8][16][8], pbl[4][8][16][8];
  int qt = blockIdx.x, h = blockIdx.y, kvh = h >> 1;
  int tid = threadIdx.x, w = tid >> 6, l = tid & 63;
  int l15 = l & 15, lq = l >> 4;
  int qb = qt * 64;
  bf16x8 qfh[8], qfl[8];
  {
    size_t qoff = (size_t)(qb + w*16 + l15)*QKV_N + h*HD_ + lq*8;
    #pragma unroll
    for (int kc = 0; kc < 8; ++kc) {
      qfh[kc] = *(const bf16x8*)(qbh + qoff + kc*32);
      qfl[kc] = *(const bf16x8*)(qbl + qoff + kc*32);
    }
  }
  f32x4 oacc[16];
  #pragma unroll
  for (int i = 0; i < 16; ++i) oacc[i] = (f32x4){0.f,0.f,0.f,0.f};
  float mrun[4] = {-1e30f,-1e30f,-1e30f,-1e30f};
  float lrun[4] = {0.f,0.f,0.f,0.f};
  for (int jt = 0; jt <= qt; ++jt) {
    int jb = jt * 64;
    #pragma unroll
    for (int i = 0; i < 8; ++i) {
      int c = i*256 + tid, kc8 = c & 31, kv = c >> 5;
      size_t goff = (size_t)(jb+kv)*QKV_N + Q_N + kvh*HD_ + kc8*8;
      *(uint4*)&kbh[kc8][kv ^ (kc8 & 7)][0] = *(const uint4*)(qbh + goff);
      *(uint4*)&kbl[kc8][kv ^ (kc8 & 7)][0] = *(const uint4*)(qbl + goff);
    }
    #pragma unroll
    for (int i = 0; i < 8; ++i) {
      int c = i*256 + tid, d = c >> 3, k8 = c & 7;
      size_t goff = ((size_t)kvh*HD_ + d)*T_S + jb + k8*8;
      *(uint4*)&vbh[k8][d ^ (k8 & 7)][0] = *(const uint4*)(vth + goff);
      *(uint4*)&vbl[k8][d ^ (k8 & 7)][0] = *(const uint4*)(vtl + goff);
    }
    __syncthreads();
    f32x4 sf[4];
    #pragma unroll
    for (int nf = 0; nf < 4; ++nf) sf[nf] = (f32x4){0.f,0.f,0.f,0.f};
    #pragma unroll
    for (int kc = 0; kc < 8; ++kc) {
      #pragma unroll
      for (int nf = 0; nf < 4; ++nf) {
        int kv = nf*16 + l15, kc8 = kc*4 + lq;
        bf16x8 kfh = *(bf16x8*)&kbh[kc8][kv ^ (kc8 & 7)][0];
        bf16x8 kfl = *(bf16x8*)&kbl[kc8][kv ^ (kc8 & 7)][0];
        sf[nf] = __builtin_amdgcn_mfma_f32_16x16x32_bf16(qfh[kc], kfh, sf[nf], 0, 0, 0);
        sf[nf] = __builtin_amdgcn_mfma_f32_16x16x32_bf16(qfh[kc], kfl, sf[nf], 0, 0, 0);
        sf[nf] = __builtin_amdgcn_mfma_f32_16x16x32_bf16(qfl[kc], kfh, sf[nf], 0, 0, 0);
      }
    }
    if (jt == qt) {
      #pragma unroll
      for (int nf = 0; nf < 4; ++nf) {
        int kvg = jb + nf*16 + l15;
        #pragma unroll
        for (int r = 0; r < 4; ++r) {
          int qg = qb + w*16 + lq*4 + r;
          if (kvg > qg) sf[nf][r] = -3.0e38f;
        }
      }
    }
    float mnew[4], scale[4], rs[4];
    #pragma unroll
    for (int r = 0; r < 4; ++r) {
      float m = fmaxf(fmaxf(sf[0][r], sf[1][r]), fmaxf(sf[2][r], sf[3][r]));
      #pragma unroll
      for (int off = 1; off < 16; off <<= 1) m = fmaxf(m, __shfl_xor(m, off));
      mnew[r] = fmaxf(mrun[r], m);
      scale[r] = __expf(mrun[r] - mnew[r]);
      rs[r] = 0.f;
    }
    #pragma unroll
    for (int nf = 0; nf < 4; ++nf)
      #pragma unroll
      for (int r = 0; r < 4; ++r) {
        float p = __expf(sf[nf][r] - mnew[r]);
        sf[nf][r] = p; rs[r] += p;
      }
    #pragma unroll
    for (int r = 0; r < 4; ++r) {
      #pragma unroll
      for (int off = 1; off < 16; off <<= 1) rs[r] += __shfl_xor(rs[r], off);
      lrun[r] = lrun[r]*scale[r] + rs[r];
      mrun[r] = mnew[r];
    }
    #pragma unroll
    for (int i = 0; i < 16; ++i) {
      oacc[i][0] *= scale[0]; oacc[i][1] *= scale[1];
      oacc[i][2] *= scale[2]; oacc[i][3] *= scale[3];
    }
    #pragma unroll
    for (int nf = 0; nf < 4; ++nf)
      #pragma unroll
      for (int r = 0; r < 4; ++r) {
        float pv = sf[nf][r];
        ushort ph, pl; split2(pv, ph, pl);
        uint mine = (uint)ph | ((uint)pl << 16);
        uint other = (uint)__shfl_xor((int)mine, 1);
        if ((l & 1) == 0) {
          int kv = nf*16 + l15, q = lq*4 + r;
          *(uint*)&pbh[w][kv>>3][q][kv&7] = (mine & 0xffffu) | ((other & 0xffffu) << 16);
          *(uint*)&pbl[w][kv>>3][q][kv&7] = (mine >> 16) | (other & 0xffff0000u);
        }
      }
    asm volatile("s_waitcnt lgkmcnt(0)" ::: "memory");
    __builtin_amdgcn_sched_barrier(0);
    #pragma unroll
    for (int k2 = 0; k2 < 2; ++k2) {
      int kc8 = k2*4 + lq;
      bf16x8 pfh = *(bf16x8*)&pbh[w][kc8][l15][0];
      bf16x8 pfl = *(bf16x8*)&pbl[w][kc8][l15][0];
      #pragma unroll
      for (int nf2 = 0; nf2 < 16; ++nf2) {
        int dl = nf2*16 + l15;
        bf16x8 vfh = *(bf16x8*)&vbh[kc8][dl ^ (kc8 & 7)][0];
        bf16x8 vfl = *(bf16x8*)&vbl[kc8][dl ^ (kc8 & 7)][0];
        oacc[nf2] = __builtin_amdgcn_mfma_f32_16x16x32_bf16(pfh, vfh, oacc[nf2], 0, 0, 0);
        oacc[nf2] = __builtin_amdgcn_mfma_f32_16x16x32_bf16(pfh, vfl, oacc[nf2], 0, 0, 0);
        oacc[nf2] = __builtin_amdgcn_mfma_f32_16x16x32_bf16(pfl, vfh, oacc[nf2], 0, 0, 0);
      }
    }
    __syncthreads();
  }
  #pragma unroll
  for (int r = 0; r < 4; ++r) {
    float inv = 1.f / lrun[r];
    int tok = qb + w*16 + lq*4 + r;
    #pragma unroll
    for (int nf2 = 0; nf2 < 16; ++nf2) {
      float o = oacc[nf2][r] * inv;
      ushort h2, l2; split2(o, h2, l2);
      ohi[(size_t)tok*Q_N + h*HD_ + nf2*16 + l15] = h2;
      olo[(size_t)tok*Q_N + h*HD_ + nf2*16 + l15] = l2;
    }
  }
}

// ---------------- O projection, split-bf16, K-sliced ----------------
__global__ __launch_bounds__(256, 2) void k_gemm_oproj(
    const ushort* __restrict__ Ah, const ushort* __restrict__ Al,
    const float* __restrict__ ow, float* __restrict__ Cp) {
  const int K = Q_N, KS = Q_N/2, NSs = KS/32;
  __shared__ ushort Ash[4][129][8], Asl[4][129][8];
  __shared__ ushort Bsh[4][65][8],  Bsl[4][65][8];
  int tid = threadIdx.x, w = tid >> 6, l = tid & 63;
  int n0 = blockIdx.x * 64, m0 = blockIdx.y * 128, kz = blockIdx.z;
  int kbase = kz * KS;
  float* C = Cp + (size_t)kz * T_S * H_DIM;
  const int l15 = l & 15, lq = l >> 4;
  const int wm = w >> 1, wn = w & 1;
  const int sar = tid >> 2, sak = tid & 3;
  const ushort* aph = Ah + (size_t)(m0 + sar)*K + kbase + sak*8;
  const ushort* apl = Al + (size_t)(m0 + sar)*K + kbase + sak*8;
  const float*  bp  = ow + (size_t)(n0 + sar)*K + kbase + sak*8;
  uint4 arh0 = *(const uint4*)(aph);
  uint4 arh1 = *(const uint4*)(aph + (size_t)64*K);
  uint4 arl0 = *(const uint4*)(apl);
  uint4 arl1 = *(const uint4*)(apl + (size_t)64*K);
  float4 brA = *(const float4*)(bp), brB = *(const float4*)(bp + 4);
  f32x4 acc[4][2];
  #pragma unroll
  for (int a = 0; a < 4; ++a)
    #pragma unroll
    for (int b = 0; b < 2; ++b) acc[a][b] = (f32x4){0.f,0.f,0.f,0.f};
  for (int t = 0; t < NSs; ++t) {
    *(uint4*)&Ash[sak][sar][0]    = arh0;
    *(uint4*)&Ash[sak][64+sar][0] = arh1;
    *(uint4*)&Asl[sak][sar][0]    = arl0;
    *(uint4*)&Asl[sak][64+sar][0] = arl1;
    { uint4 H, L; split8(brA, brB, H, L);
      *(uint4*)&Bsh[sak][sar][0] = H;
      *(uint4*)&Bsl[sak][sar][0] = L; }
    __syncthreads();
    if (t + 1 < NSs) {
      int k0 = (t+1)*32;
      arh0 = *(const uint4*)(aph + k0);
      arh1 = *(const uint4*)(aph + (size_t)64*K + k0);
      arl0 = *(const uint4*)(apl + k0);
      arl1 = *(const uint4*)(apl + (size_t)64*K + k0);
      brA = *(const float4*)(bp + k0); brB = *(const float4*)(bp + k0 + 4);
    }
    bf16x8 bh[2], bl[2];
    #pragma unroll
    for (int nf = 0; nf < 2; ++nf) {
      bh[nf] = *(bf16x8*)&Bsh[lq][wn*32 + nf*16 + l15][0];
      bl[nf] = *(bf16x8*)&Bsl[lq][wn*32 + nf*16 + l15][0];
    }
    #pragma unroll
    for (int mf = 0; mf < 4; ++mf) {
      bf16x8 ah = *(bf16x8*)&Ash[lq][wm*64 + mf*16 + l15][0];
      bf16x8 al = *(bf16x8*)&Asl[lq][wm*64 + mf*16 + l15][0];
      #pragma unroll
      for (int nf = 0; nf < 2; ++nf) {
        acc[mf][nf] = __builtin_amdgcn_mfma_f32_16x16x32_bf16(ah, bh[nf], acc[mf][nf], 0, 0, 0);
        acc[mf][nf] = __builtin_amdgcn_mfma_f32_16x16x32_bf16(ah, bl[nf], acc[mf][nf], 0, 0, 0);
        acc[mf][nf] = __builtin_amdgcn_mfma_f32_16x16x32_bf16(al, bh[nf], acc[mf][nf], 0, 0, 0);
      }
    }
    __syncthreads();
  }
  #pragma unroll
  for (int mf = 0; mf < 4; ++mf)
    #pragma unroll
    for (int nf = 0; nf < 2; ++nf)
      #pragma unroll
      for (int r = 0; r < 4; ++r)
        C[(size_t)(m0 + wm*64 + mf*16 + lq*4 + r)*H_DIM + n0 + wn*32 + nf*16 + l15] = acc[mf][nf][r];
}

__global__ void k_zero_counts(int* counts) {
  if (threadIdx.x < N_E) counts[threadIdx.x] = 0;
}

// ---------------- post-attn + residual + pre-ffn + router (fp32, sums 2 K-slices) ----------------
__global__ __launch_bounds__(256) void k_fuse_router(
    const float* __restrict__ hid, const float* __restrict__ aproj0,
    const float* __restrict__ aproj1,
    const float* __restrict__ w_pa, const float* __restrict__ w_pf,
    const float* __restrict__ rscale, const float* __restrict__ rw,
    float* __restrict__ xout, ushort* __restrict__ tbf,
    float* __restrict__ topw, int* __restrict__ counts, int* __restrict__ lists) {
  __shared__ float sm[4];
  __shared__ float nrow[H_DIM];
  __shared__ float lg[N_E];
  int t = blockIdx.x, tid = threadIdx.x;
  float ap[11], hd[11]; float s = 0.f;
  #pragma unroll
  for (int j = 0; j < 11; ++j) {
    int idx = tid + j*256;
    ap[j] = aproj0[(size_t)t*H_DIM + idx] + aproj1[(size_t)t*H_DIM + idx];
    hd[j] = hid[(size_t)t*H_DIM + idx];
    s += ap[j]*ap[j];
  }
  s = block_sum256(s, sm);
  float r1 = rsqrtf(s / (float)H_DIM + EPS_);
  float x[11]; float s2 = 0.f;
  #pragma unroll
  for (int j = 0; j < 11; ++j) {
    int idx = tid + j*256;
    x[j] = hd[j] + ap[j]*r1*w_pa[idx];
    s2 += x[j]*x[j];
    xout[(size_t)t*H_DIM + idx] = x[j];
  }
  s2 = block_sum256(s2, sm);
  float r2 = rsqrtf(s2 / (float)H_DIM + EPS_);
  float tv[11]; float s3 = 0.f;
  #pragma unroll
  for (int j = 0; j < 11; ++j) {
    int idx = tid + j*256;
    tv[j] = x[j]*r2*w_pf[idx];
    s3 += tv[j]*tv[j];
    tbf[(size_t)t*H_DIM + idx] = f2bf(tv[j]);
  }
  s3 = block_sum256(s3, sm);
  float r3 = rsqrtf(s3 / (float)H_DIM + EPS_) * rsqrtf((float)H_DIM);
  #pragma unroll
  for (int j = 0; j < 11; ++j) {
    int idx = tid + j*256;
    nrow[idx] = tv[j]*r3*rscale[idx];
  }
  __syncthreads();
  int w = tid >> 6, l = tid & 63;
  #pragma unroll
  for (int ei = 0; ei < 8; ++ei) {
    int e = w*8 + ei;
    const float* rwp = rw + (size_t)e*H_DIM;
    float p = 0.f;
    #pragma unroll 4
    for (int j = 0; j < 44; ++j) p += nrow[l + j*64] * rwp[l + j*64];
    p = wave_sum(p);
    if (l == 0) lg[e] = p;
  }
  __syncthreads();
  if (w == 0) {
    float le = (l < 32) ? lg[l] : -3e38f;
    float m = le;
    #pragma unroll
    for (int off = 1; off < 64; off <<= 1) m = fmaxf(m, __shfl_xor(m, off));
    float p = (l < 32) ? __expf(le - m) : -2.f;
    float v = p; int vi = (l < 32) ? l : 999;
    float selv[TOPK_]; int seli[TOPK_];
    for (int sx = 0; sx < TOPK_; ++sx) {
      float bv = v; int bi = vi;
      #pragma unroll
      for (int off = 1; off < 64; off <<= 1) {
        float ov = __shfl_xor(bv, off); int oi = __shfl_xor(bi, off);
        if (ov > bv || (ov == bv && oi < bi)) { bv = ov; bi = oi; }
      }
      selv[sx] = bv; seli[sx] = bi;
      if (vi == bi) v = -1.f;
    }
    if (l == 0) {
      float wsum = selv[0]+selv[1]+selv[2]+selv[3];
      for (int sx = 0; sx < TOPK_; ++sx) {
        topw[t*TOPK_ + sx] = selv[sx]/wsum;
        int e = seli[sx];
        int pos = atomicAdd(&counts[e], 1);
        lists[e*T_S + pos] = t*TOPK_ + sx;
      }
    }
  }
}

// ---------------- MoE stage 1: M=128, N=64(g+u), K-split 4, coalesced staging ----------------
// grid (11, 32, 16): n0=bx*64, e=by, mz=bz>>2, kz=bz&3; 256 thr, 4 waves (2M x 2N)
__global__ __launch_bounds__(256, 4) void k_moe_gateup(
    const ushort* __restrict__ tbf, const float* __restrict__ wg,
    const float* __restrict__ wu, const int* __restrict__ counts,
    const int* __restrict__ lists, float* __restrict__ pg, float* __restrict__ pu) {
  const int K = H_DIM, KS = K/4, NS = KS/32;   // 704, 22
  __shared__ ushort As[2][4][129][8];
  __shared__ ushort Bg[2][4][65][8], Bu[2][4][65][8];
  __shared__ int lls[128];
  int tid = threadIdx.x, w = tid >> 6, l = tid & 63;
  int e = blockIdx.y, n0 = blockIdx.x * 64;
  int mz = blockIdx.z >> 2, kz = blockIdx.z & 3;
  int m0 = mz * 128, kbase = kz * KS;
  int ne = counts[e];
  if (m0 >= ne) return;
  const int* list = lists + e*T_S;
  if (tid < 128) lls[tid] = (m0 + tid < ne) ? list[m0 + tid] : list[0];
  __syncthreads();
  const int l15 = l & 15, lq = l >> 4;
  const int wm = w >> 1, wn = w & 1;
  // A: 4 lanes/row x 16B contiguous; rows ar and ar+64
  const int ar = tid >> 2, akq = tid & 3;
  const ushort* ap0 = tbf + (size_t)(lls[ar]      >> 2)*K + kbase + akq*8;
  const ushort* ap1 = tbf + (size_t)(lls[ar + 64] >> 2)*K + kbase + akq*8;
  // B: 8 lanes/row x 16B contiguous; rows br and br+32 of each of gate/up
  const int br = tid >> 3, oc = tid & 7;
  const float* gp0 = wg + ((size_t)e*I_DIM + n0 + br)*K + kbase + oc*4;
  const float* gp1 = gp0 + (size_t)32*K;
  const float* up0 = wu + ((size_t)e*I_DIM + n0 + br)*K + kbase + oc*4;
  const float* up1 = up0 + (size_t)32*K;
  uint4 a0, a1; float4 g0, g1, u0, u1;
  auto LOADR = [&](int t) {
    int k0 = t*32;
    a0 = *(const uint4*)(ap0 + k0); a1 = *(const uint4*)(ap1 + k0);
    g0 = *(const float4*)(gp0 + k0); g1 = *(const float4*)(gp1 + k0);
    u0 = *(const float4*)(up0 + k0); u1 = *(const float4*)(up1 + k0);
  };
  auto STAGE = [&](int buf) {
    *(uint4*)&As[buf][akq][ar][0]      = a0;
    *(uint4*)&As[buf][akq][ar + 64][0] = a1;
    int pl = oc >> 1, sub = (oc & 1) * 4;
    *(ushort4*)&Bg[buf][pl][br][sub]      = pack4(g0);
    *(ushort4*)&Bg[buf][pl][br + 32][sub] = pack4(g1);
    *(ushort4*)&Bu[buf][pl][br][sub]      = pack4(u0);
    *(ushort4*)&Bu[buf][pl][br + 32][sub] = pack4(u1);
  };
  f32x4 ag[4][2], au[4][2];
  #pragma unroll
  for (int a = 0; a < 4; ++a)
    #pragma unroll
    for (int b = 0; b < 2; ++b) { ag[a][b] = (f32x4){0.f,0.f,0.f,0.f}; au[a][b] = (f32x4){0.f,0.f,0.f,0.f}; }
  LOADR(0); STAGE(0); LOADR(1);
  __syncthreads();
  for (int t = 0; t < NS; ++t) {
    int cur = t & 1;
    if (t + 1 < NS) STAGE(cur ^ 1);
    if (t + 2 < NS) LOADR(t + 2);
    bf16x8 bgf[2], buf_[2];
    #pragma unroll
    for (int nf = 0; nf < 2; ++nf) {
      bgf[nf]  = *(bf16x8*)&Bg[cur][lq][wn*32 + nf*16 + l15][0];
      buf_[nf] = *(bf16x8*)&Bu[cur][lq][wn*32 + nf*16 + l15][0];
    }
    #pragma unroll
    for (int mf = 0; mf < 4; ++mf) {
      bf16x8 af = *(bf16x8*)&As[cur][lq][wm*64 + mf*16 + l15][0];
      #pragma unroll
      for (int nf = 0; nf < 2; ++nf) {
        ag[mf][nf] = __builtin_amdgcn_mfma_f32_16x16x32_bf16(af, bgf[nf],  ag[mf][nf], 0, 0, 0);
        au[mf][nf] = __builtin_amdgcn_mfma_f32_16x16x32_bf16(af, buf_[nf], au[mf][nf], 0, 0, 0);
      }
    }
    __syncthreads();
  }
  const size_t PSL = (size_t)NSLOT * I_DIM;
  #pragma unroll
  for (int mf = 0; mf < 4; ++mf)
    #pragma unroll
    for (int r = 0; r < 4; ++r) {
      int row = wm*64 + mf*16 + lq*4 + r;
      if (m0 + row < ne) {
        size_t base = (size_t)kz*PSL + (size_t)lls[row]*I_DIM + n0 + wn*32;
        #pragma unroll
        for (int nf = 0; nf < 2; ++nf) {
          pg[base + nf*16 + l15] = ag[mf][nf][r];
          pu[base + nf*16 + l15] = au[mf][nf][r];
        }
      }
    }
}

// ---------------- gelu-reduce: sum 4 K-slices, gelu(g)*u -> bf16 abf ----------------
__global__ __launch_bounds__(192) void k_gelu_reduce(
    const float* __restrict__ pg, const float* __restrict__ pu,
    ushort* __restrict__ abf) {
  int sidx = blockIdx.x, c = threadIdx.x;
  if (c >= 176) return;
  const size_t S4 = (size_t)NSLOT * I_DIM / 4;
  const float4* g = (const float4*)(pg + (size_t)sidx*I_DIM) + c;
  const float4* u = (const float4*)(pu + (size_t)sidx*I_DIM) + c;
  float4 gs = g[0], us = u[0];
  #pragma unroll
  for (int k = 1; k < 4; ++k) {
    float4 gk = g[k*S4], uk = u[k*S4];
    gs.x += gk.x; gs.y += gk.y; gs.z += gk.z; gs.w += gk.w;
    us.x += uk.x; us.y += uk.y; us.z += uk.z; us.w += uk.w;
  }
  float go[4] = {gs.x, gs.y, gs.z, gs.w}, uo[4] = {us.x, us.y, us.z, us.w};
  ushort o[4];
  #pragma unroll
  for (int i = 0; i < 4; ++i) {
    float gg = go[i];
    float th = tanhf(0.7978845608f*(gg + 0.044715f*gg*gg*gg));
    o[i] = f2bf(0.5f*gg*(1.f + th)*uo[i]);
  }
  *(ushort4*)(abf + (size_t)sidx*I_DIM + c*4) = *(ushort4*)o;
}

// ---------------- MoE stage 2: M=128, N=128, K-split 2, coalesced staging ----------------
// grid (22, 32, 8): n0=bx*128, e=by, mz=bz>>1, kz=bz&1; 256 thr, 4 waves (2M x 2N)
__global__ __launch_bounds__(256, 4) void k_moe_down(
    const ushort* __restrict__ abf, const float* __restrict__ wd,
    const int* __restrict__ counts, const int* __restrict__ lists,
    float* __restrict__ yp) {
  const int K = I_DIM, KS = K/2, NS = KS/32;   // 352, 11
  __shared__ ushort As[2][4][129][8];
  __shared__ ushort Bs[2][4][129][8];
  __shared__ int lls[128];
  int tid = threadIdx.x, w = tid >> 6, l = tid & 63;
  int e = blockIdx.y, n0 = blockIdx.x * 128;
  int mz = blockIdx.z >> 1, kz = blockIdx.z & 1;
  int m0 = mz * 128, kbase = kz * KS;
  int ne = counts[e];
  if (m0 >= ne) return;
  const int* list = lists + e*T_S;
  if (tid < 128) lls[tid] = (m0 + tid < ne) ? list[m0 + tid] : 0;
  __syncthreads();
  const int l15 = l & 15, lq = l >> 4;
  const int wm = w >> 1, wn = w & 1;
  // A: 4 lanes/row x 16B contiguous; rows ar and ar+64
  const int ar = tid >> 2, akq = tid & 3;
  const ushort* ap0 = abf + (size_t)lls[ar]*K      + kbase + akq*8;
  const ushort* ap1 = abf + (size_t)lls[ar + 64]*K + kbase + akq*8;
  // B: 8 lanes/row x 16B contiguous; rows br, br+32, br+64, br+96
  const int br = tid >> 3, oc = tid & 7;
  const float* bp0 = wd + ((size_t)e*H_DIM + n0 + br)*K + kbase + oc*4;
  const float* bp1 = bp0 + (size_t)32*K;
  const float* bp2 = bp0 + (size_t)64*K;
  const float* bp3 = bp0 + (size_t)96*K;
  uint4 a0, a1; float4 c0, c1, c2, c3;
  auto LOADR = [&](int t) {
    int k0 = t*32;
    a0 = *(const uint4*)(ap0 + k0); a1 = *(const uint4*)(ap1 + k0);
    c0 = *(const float4*)(bp0 + k0); c1 = *(const float4*)(bp1 + k0);
    c2 = *(const float4*)(bp2 + k0); c3 = *(const float4*)(bp3 + k0);
  };
  auto STAGE = [&](int buf) {
    *(uint4*)&As[buf][akq][ar][0]      = a0;
    *(uint4*)&As[buf][akq][ar + 64][0] = a1;
    int pl = oc >> 1, sub = (oc & 1) * 4;
    *(ushort4*)&Bs[buf][pl][br][sub]      = pack4(c0);
    *(ushort4*)&Bs[buf][pl][br + 32][sub] = pack4(c1);
    *(ushort4*)&Bs[buf][pl][br + 64][sub] = pack4(c2);
    *(ushort4*)&Bs[buf][pl][br + 96][sub] = pack4(c3);
  };
  f32x4 acc[4][4];
  #pragma unroll
  for (int a = 0; a < 4; ++a)
    #pragma unroll
    for (int b = 0; b < 4; ++b) acc[a][b] = (f32x4){0.f,0.f,0.f,0.f};
  LOADR(0); STAGE(0); LOADR(1);
  __syncthreads();
  for (int t = 0; t < NS; ++t) {
    int cur = t & 1;
    if (t + 1 < NS) STAGE(cur ^ 1);
    if (t + 2 < NS) LOADR(t + 2);
    bf16x8 bf[4];
    #pragma unroll
    for (int nf = 0; nf < 4; ++nf)
      bf[nf] = *(bf16x8*)&Bs[cur][lq][wn*64 + nf*16 + l15][0];
    #pragma unroll
    for (int mf = 0; mf < 4; ++mf) {
      bf16x8 af = *(bf16x8*)&As[cur][lq][wm*64 + mf*16 + l15][0];
      #pragma unroll
      for (int nf = 0; nf < 4; ++nf)
        acc[mf][nf] = __builtin_amdgcn_mfma_f32_16x16x32_bf16(af, bf[nf], acc[mf][nf], 0, 0, 0);
    }
    __syncthreads();
  }
  const size_t YSL = (size_t)NSLOT * H_DIM;
  #pragma unroll
  for (int mf = 0; mf < 4; ++mf)
    #pragma unroll
    for (int r = 0; r < 4; ++r) {
      int row = wm*64 + mf*16 + lq*4 + r;
      if (m0 + row < ne) {
        size_t base = (size_t)kz*YSL + (size_t)lls[row]*H_DIM + n0 + wn*64;
        #pragma unroll
        for (int nf = 0; nf < 4; ++nf)
          yp[base + nf*16 + l15] = acc[mf][nf][r];
      }
    }
}

// ---------------- combine (sums 2 down K-slices) + post-ffn rmsnorm + residual ----------------
__global__ __launch_bounds__(256) void k_combine(
    const float* __restrict__ yp, const float* __restrict__ topw,
    const float* __restrict__ xin, const float* __restrict__ w_pff,
    float* __restrict__ out) {
  __shared__ float sm[4];
  const size_t YSL = (size_t)NSLOT * H_DIM;
  int t = blockIdx.x, tid = threadIdx.x;
  float w0 = topw[t*4+0], w1 = topw[t*4+1], w2 = topw[t*4+2], w3 = topw[t*4+3];
  const float* y0 = yp + (size_t)(t*4+0)*H_DIM;
  const float* y1 = yp + (size_t)(t*4+1)*H_DIM;
  const float* y2 = yp + (size_t)(t*4+2)*H_DIM;
  const float* y3 = yp + (size_t)(t*4+3)*H_DIM;
  float m[11]; float s = 0.f;
  #pragma unroll
  for (int j = 0; j < 11; ++j) {
    int idx = tid + j*256;
    m[j] = w0*(y0[idx]+y0[YSL+idx]) + w1*(y1[idx]+y1[YSL+idx])
         + w2*(y2[idx]+y2[YSL+idx]) + w3*(y3[idx]+y3[YSL+idx]);
    s += m[j]*m[j];
  }
  s = block_sum256(s, sm);
  float r = rsqrtf(s / (float)H_DIM + EPS_);
  #pragma unroll
  for (int j = 0; j < 11; ++j) {
    int idx = tid + j*256;
    out[(size_t)t*H_DIM + idx] = xin[(size_t)t*H_DIM + idx] + m[j]*r*w_pff[idx];
  }
}

extern "C" void kernel_launch(void* const* d_in, const int* in_sizes, int n_in,
                              void* d_out, int out_size, void* d_ws, size_t ws_size,
                              hipStream_t stream) {
  (void)in_sizes; (void)n_in; (void)out_size; (void)ws_size;
  const float* hid   = (const float*)d_in[0];
  const float* cosb  = (const float*)d_in[1];
  const float* sinb  = (const float*)d_in[2];
  const float* w_in  = (const float*)d_in[3];
  const float* w_pa  = (const float*)d_in[4];
  const float* w_pf  = (const float*)d_in[5];
  const float* w_pff = (const float*)d_in[6];
  const float* qw    = (const float*)d_in[7];
  const float* kw    = (const float*)d_in[8];
  const float* vw    = (const float*)d_in[9];
  const float* ow    = (const float*)d_in[10];
  const float* qnw   = (const float*)d_in[11];
  const float* knw   = (const float*)d_in[12];
  const float* rw    = (const float*)d_in[13];
  const float* rsc   = (const float*)d_in[14];
  const float* wg    = (const float*)d_in[15];
  const float* wu    = (const float*)d_in[16];
  const float* wd    = (const float*)d_in[17];

  char* ws = (char*)d_ws;
  size_t off = 0;
  auto alloc = [&](size_t sz) { size_t o = off; off += (sz + 255) & ~(size_t)255; return o; };
  size_t oR1  = alloc(46137344);
  size_t ohh  = alloc((size_t)T_S*H_DIM*2);
  size_t ohl  = alloc((size_t)T_S*H_DIM*2);
  size_t oqh  = alloc((size_t)T_S*QKV_N*2);
  size_t oql  = alloc((size_t)T_S*QKV_N*2);
  size_t ovh  = alloc((size_t)8*HD_*T_S*2);
  size_t ovl  = alloc((size_t)8*HD_*T_S*2);
  size_t ox   = alloc((size_t)T_S*H_DIM*4);
  size_t otbf = alloc((size_t)T_S*H_DIM*2);
  size_t otw  = alloc((size_t)T_S*TOPK_*4);
  size_t ocnt = alloc((size_t)N_E*4);
  size_t olst = alloc((size_t)N_E*T_S*4);

  const size_t APRJ_SLICE = (size_t)T_S * H_DIM * 4;

  float*  qkvf0 = (float*)(ws + oR1);
  float*  qkvf1 = (float*)(ws + oR1 + 16777216);
  ushort* o_hi  = (ushort*)(ws + oR1);
  ushort* o_lo  = (ushort*)(ws + oR1 + 4194304);
  float*  aprj0 = (float*)(ws + oR1 + 8388608);
  float*  aprj1 = (float*)(ws + oR1 + 8388608 + APRJ_SLICE);
  float*  pg    = (float*)(ws + oR1);
  float*  pu    = (float*)(ws + oR1 + 23068672);
  float*  yp    = (float*)(ws + oR1);
  ushort* abf   = (ushort*)(ws + ohh);

  k_ln_in<<<dim3(T_S), dim3(256), 0, stream>>>(hid, w_in, (ushort*)(ws+ohh), (ushort*)(ws+ohl));
  k_gemm_qkv<<<dim3(128, 4, 2), dim3(256), 0, stream>>>((ushort*)(ws+ohh), (ushort*)(ws+ohl),
                                                        qw, kw, vw, qkvf0);
  k_norm_rope<<<dim3(T_S*32), dim3(64), 0, stream>>>(qkvf0, qkvf1, cosb, sinb, qnw, knw,
                                                     (ushort*)(ws+oqh), (ushort*)(ws+oql),
                                                     (ushort*)(ws+ovh), (ushort*)(ws+ovl));
  k_attn<<<dim3(8, 16), dim3(256), 0, stream>>>((ushort*)(ws+oqh), (ushort*)(ws+oql),
                                                (ushort*)(ws+ovh), (ushort*)(ws+ovl), o_hi, o_lo);
  k_gemm_oproj<<<dim3(44, 4, 2), dim3(256), 0, stream>>>(o_hi, o_lo, ow, aprj0);
  k_zero_counts<<<dim3(1), dim3(64), 0, stream>>>((int*)(ws+ocnt));
  k_fuse_router<<<dim3(T_S), dim3(256), 0, stream>>>(hid, aprj0, aprj1, w_pa, w_pf, rsc, rw,
                                                     (float*)(ws+ox), (ushort*)(ws+otbf),
                                                     (float*)(ws+otw), (int*)(ws+ocnt), (int*)(ws+olst));
  k_moe_gateup<<<dim3(11, N_E, 16), dim3(256), 0, stream>>>((ushort*)(ws+otbf), wg, wu,
                                                            (int*)(ws+ocnt), (int*)(ws+olst), pg, pu);
  k_gelu_reduce<<<dim3(NSLOT), dim3(192), 0, stream>>>(pg, pu, abf);
  k_moe_down<<<dim3(22, N_E, 8), dim3(256), 0, stream>>>(abf, wd,
                                                         (int*)(ws+ocnt), (int*)(ws+olst), yp);
  k_combine<<<dim3(T_S), dim3(256), 0, stream>>>(yp, (float*)(ws+otw), (float*)(ws+ox),
                                                 w_pff, (float*)d_out);
}